// Round 2
// baseline (652.131 us; speedup 1.0000x reference)
//
#include <hip/hip_runtime.h>
#include <cstdint>
#include <cstddef>

#define T_TOK 4096
#define HD 2048
#define ID 1408
#define NE 8
#define NA (T_TOK * 2)        // 8192 assignments (K=2)
#define MAXR 10240            // 8192 + 8*255 padding headroom, mult of 256
#define MAXT 40               // max 256-row tiles (<= 39 actually)
#define EIH ((size_t)NE * ID * HD)
#define N4 ((int)(EIH / 4))   // float4 count per weight tensor = 5,767,168
#define NCGU 2048             // cast blocks for gate+up (merged with gather)
#define NCASTD 512            // cast blocks for down (merged with gateup, 512 thr)
#define NTILE_G (MAXR / 256)  // 40
#define NGEMM_GU (NTILE_G * (ID / 128))  // 440 (divisible by 8 -> bijective XCD swizzle)
#define NKGU (HD / 32)        // 64 K-tiles
#define NKD  (ID / 32)        // 44 K-tiles

typedef __bf16 bf16x8 __attribute__((ext_vector_type(8)));
typedef float f32x4 __attribute__((ext_vector_type(4)));

__device__ __forceinline__ unsigned short f2bf(float f) {
  union { float f; unsigned int u; } c; c.f = f;
  unsigned int u = c.u;
  u += 0x7fffu + ((u >> 16) & 1u);   // round-to-nearest-even
  return (unsigned short)(u >> 16);
}

__device__ __forceinline__ void gl_lds16(const unsigned short* g, unsigned short* l) {
  __builtin_amdgcn_global_load_lds(
      (const __attribute__((address_space(1))) unsigned int*)g,
      (__attribute__((address_space(3))) unsigned int*)l, 16, 0, 0);
}

// XOR-swizzled Nx32 bf16 tile (64B rows, swizzle at 128B/2-row units):
// logical (row R, 16B chunk fq) lives at physical chunk p = q ^ ((R>>1)&7),
// q = (R&1)*4 + fq. Measured conflict-free (SQ_LDS_BANK_CONFLICT = 0).
__device__ __forceinline__ int swz_off(int R, int fq) {
  int q = ((R & 1) << 2) | fq;
  int p = q ^ ((R >> 1) & 7);
  return (R >> 1) * 64 + p * 8;
}

// ---------------- routing ---------------------------------------------------
__global__ void moe_count(const int* __restrict__ idx, int* __restrict__ cnt) {
  int a = blockIdx.x * 256 + threadIdx.x;
  if (a < NA) atomicAdd(&cnt[idx[a]], 1);
}

__global__ void moe_scan(const int* __restrict__ cnt, int* __restrict__ seg,
                         int* __restrict__ work_e, int* __restrict__ work_r,
                         int* __restrict__ ntiles) {
  if (blockIdx.x == 0 && threadIdx.x == 0) {
    int off = 0, nt = 0;
    for (int e = 0; e < NE; ++e) {
      seg[e] = off;
      int c = cnt[e];
      int tiles = (c + 255) >> 8;          // pad each expert to 256-row tiles
      for (int tb = 0; tb < tiles; ++tb) {
        work_e[nt] = e;
        work_r[nt] = off + tb * 256;
        ++nt;
      }
      off += tiles << 8;
    }
    *ntiles = nt;
  }
}

__global__ void moe_fill(const int* __restrict__ idx, const float* __restrict__ wts,
                         const int* __restrict__ seg, int* __restrict__ cnt2,
                         int* __restrict__ row_token, float* __restrict__ row_weight,
                         int* __restrict__ slot_of) {
  int a = blockIdx.x * 256 + threadIdx.x;
  if (a < NA) {
    int e = idx[a];
    int pos = atomicAdd(&cnt2[e], 1);
    int slot = seg[e] + pos;
    row_token[slot] = a >> 1;       // token id (K=2)
    row_weight[slot] = wts[a];
    slot_of[a] = slot;
  }
}

// ---------------- mega1: gather routed rows  +  cast gate/up fp32->bf16 ----
__global__ void mega_gather_castgu(
    const float* __restrict__ hidden, const int* __restrict__ slot_of,
    unsigned short* __restrict__ Xg,
    const float* __restrict__ gate_w, const float* __restrict__ up_w,
    unsigned short* __restrict__ gate_bf, unsigned short* __restrict__ ub_out) {
  const int bx = blockIdx.x;
  if (bx < NA) {
    const int slot = slot_of[bx];
    const int t = bx >> 1;
    const float4* src = (const float4*)(hidden + (size_t)t * HD);
    ushort4* dst = (ushort4*)(Xg + (size_t)slot * HD);
#pragma unroll
    for (int j = 0; j < 2; ++j) {
      int i = threadIdx.x + j * 256;
      float4 v = src[i];
      ushort4 o;
      o.x = f2bf(v.x); o.y = f2bf(v.y); o.z = f2bf(v.z); o.w = f2bf(v.w);
      dst[i] = o;
    }
  } else {
    const int cb = bx - NA;
    const int total = 2 * N4;
    for (int i = cb * 256 + threadIdx.x; i < total; i += NCGU * 256) {
      const float* s; unsigned short* t; int j = i;
      if (j < N4) { s = gate_w; t = gate_bf; }
      else { s = up_w; t = ub_out; j -= N4; }
      f32x4 v = __builtin_nontemporal_load((const f32x4*)s + j);
      ushort4 o;
      o.x = f2bf(v[0]); o.y = f2bf(v[1]); o.z = f2bf(v[2]); o.w = f2bf(v[3]);
      ((ushort4*)t)[j] = o;
    }
  }
}

// ---------------- mega2: gate+up GEMM (SwiGLU epilogue) + cast down_w ------
// Tile: 256 rows x 128 I-cols, both gate and up. 8 waves (2M x 4N): wave owns
// 128 rows x 32 cols of BOTH gate and up (SwiGLU stays in-wave).
// BK=32, 3 LDS buffers, 2 phases/K-tile, stage tile t+2, vmcnt(4) steady.
__global__ __launch_bounds__(512, 2) void moe_gateup(
    const unsigned short* __restrict__ Xg,
    const unsigned short* __restrict__ Wg,
    const unsigned short* __restrict__ Wu,
    unsigned short* __restrict__ inter,
    const int* __restrict__ work_e, const int* __restrict__ work_r,
    const int* __restrict__ ntiles,
    const float* __restrict__ down_w, unsigned short* __restrict__ down_bf) {
  const int bx = blockIdx.x;
  if (bx >= NGEMM_GU) {
    // down-cast backfills the GEMM tail rounds
    const int cb = bx - NGEMM_GU;
    for (int i = cb * 512 + threadIdx.x; i < N4; i += NCASTD * 512) {
      f32x4 v = __builtin_nontemporal_load((const f32x4*)down_w + i);
      ushort4 o;
      o.x = f2bf(v[0]); o.y = f2bf(v[1]); o.z = f2bf(v[2]); o.w = f2bf(v[3]);
      ((ushort4*)down_bf)[i] = o;
    }
    return;
  }
  // bijective XCD swizzle (440 % 8 == 0); consecutive g share the B panel
  const int g = (bx & 7) * (NGEMM_GU / 8) + (bx >> 3);
  const int tile = g % NTILE_G;
  if (tile >= *ntiles) return;
  const int e = work_e[tile];
  const int row0 = work_r[tile];
  const int col0 = (g / NTILE_G) * 128;

  __shared__ unsigned short As[3][256 * 32];   // 48 KB
  __shared__ unsigned short Bs[3][256 * 32];   // 48 KB (rows 0-127 gate, 128-255 up)

  const int tid = threadIdx.x;
  const int lane = tid & 63;
  const int wave = tid >> 6;          // 0..7
  const int wm = wave >> 2, wn = wave & 3;
  const int p_l = lane & 7;
  const int ub  = lane >> 3;
  const int q_l = p_l ^ ub;
  const int srow = (ub << 1) | (q_l >> 2);
  const int scol = (q_l & 3) << 3;
  const int fm = lane & 15, fq = lane >> 4;

  const size_t a_base = (size_t)row0 * HD;
  const size_t b_base = ((size_t)e * ID + col0) * HD;

  f32x4 zero = {0.f, 0.f, 0.f, 0.f};
  f32x4 accg[8][2], accu[8][2];
#pragma unroll
  for (int mi = 0; mi < 8; ++mi)
#pragma unroll
    for (int ni = 0; ni < 2; ++ni) { accg[mi][ni] = zero; accu[mi][ni] = zero; }

  auto stageA = [&](int k0, int b) {
#pragma unroll
    for (int j = 0; j < 2; ++j) {
      const int rb = j * 128 + wave * 16;
      gl_lds16(Xg + a_base + (size_t)(rb + srow) * HD + k0 + scol, &As[b][rb * 32]);
    }
  };
  auto stageB = [&](int k0, int b) {
    const int rb = wave * 16;
    gl_lds16(Wg + b_base + (size_t)(rb + srow) * HD + k0 + scol, &Bs[b][rb * 32]);
    gl_lds16(Wu + b_base + (size_t)(rb + srow) * HD + k0 + scol, &Bs[b][(128 + rb) * 32]);
  };

  // prologue: tiles 0 and 1 (8 loads); wait tile 0 (4 still in flight)
  stageA(0, 0); stageB(0, 0);
  stageA(32, 1); stageB(32, 1);
  asm volatile("s_waitcnt vmcnt(4)" ::: "memory");
  __builtin_amdgcn_s_barrier();
  __builtin_amdgcn_sched_barrier(0);

  int bufc = 0, buf2 = 2, k2 = 64;
  bf16x8 bg[2], bu[2];
#pragma unroll 1
  for (int t = 0; t < NKGU; ++t) {
    // ---- phase 0: stage A(t+2) | read B + A[0-3] | 16 MFMA ----
    if (t + 2 < NKGU) stageA(k2, buf2);
    {
      bf16x8 af[4];
#pragma unroll
      for (int i = 0; i < 2; ++i) {
        bg[i] = *(const bf16x8*)&Bs[bufc][swz_off(wn * 32 + i * 16 + fm, fq)];
        bu[i] = *(const bf16x8*)&Bs[bufc][swz_off(128 + wn * 32 + i * 16 + fm, fq)];
      }
#pragma unroll
      for (int i = 0; i < 4; ++i)
        af[i] = *(const bf16x8*)&As[bufc][swz_off(wm * 128 + i * 16 + fm, fq)];
      __builtin_amdgcn_s_setprio(1);
#pragma unroll
      for (int mi = 0; mi < 4; ++mi)
#pragma unroll
        for (int ni = 0; ni < 2; ++ni) {
          accg[mi][ni] = __builtin_amdgcn_mfma_f32_16x16x32_bf16(af[mi], bg[ni], accg[mi][ni], 0, 0, 0);
          accu[mi][ni] = __builtin_amdgcn_mfma_f32_16x16x32_bf16(af[mi], bu[ni], accu[mi][ni], 0, 0, 0);
        }
      __builtin_amdgcn_s_setprio(0);
    }
    __builtin_amdgcn_s_barrier();
    __builtin_amdgcn_sched_barrier(0);
    // ---- phase 1: stage B(t+2) | read A[4-7] | 16 MFMA ----
    if (t + 2 < NKGU) stageB(k2, buf2);
    {
      bf16x8 af[4];
#pragma unroll
      for (int i = 0; i < 4; ++i)
        af[i] = *(const bf16x8*)&As[bufc][swz_off(wm * 128 + (4 + i) * 16 + fm, fq)];
      __builtin_amdgcn_s_setprio(1);
#pragma unroll
      for (int mi = 0; mi < 4; ++mi)
#pragma unroll
        for (int ni = 0; ni < 2; ++ni) {
          accg[4 + mi][ni] = __builtin_amdgcn_mfma_f32_16x16x32_bf16(af[mi], bg[ni], accg[4 + mi][ni], 0, 0, 0);
          accu[4 + mi][ni] = __builtin_amdgcn_mfma_f32_16x16x32_bf16(af[mi], bu[ni], accu[4 + mi][ni], 0, 0, 0);
        }
      __builtin_amdgcn_s_setprio(0);
    }
    if (t < NKGU - 1) {
      if (t + 2 < NKGU) asm volatile("s_waitcnt vmcnt(4)" ::: "memory");
      else              asm volatile("s_waitcnt vmcnt(0)" ::: "memory");
      __builtin_amdgcn_s_barrier();
      __builtin_amdgcn_sched_barrier(0);
    }
    k2 += 32;
    bufc = (bufc == 2) ? 0 : bufc + 1;
    buf2 = (buf2 == 2) ? 0 : buf2 + 1;
  }

  // SwiGLU epilogue -> inter (bf16). Padded rows computed too (harmless).
#pragma unroll
  for (int mi = 0; mi < 8; ++mi)
#pragma unroll
    for (int ni = 0; ni < 2; ++ni)
#pragma unroll
      for (int r = 0; r < 4; ++r) {
        float gg = accg[mi][ni][r];
        float u = accu[mi][ni][r];
        float v = (gg / (1.0f + __expf(-gg))) * u;
        int row = row0 + wm * 128 + mi * 16 + fq * 4 + r;
        int col = col0 + wn * 32 + ni * 16 + fm;
        inter[(size_t)row * ID + col] = f2bf(v);
      }
}

// ---------------- phase B: down GEMM, weighted atomic scatter ---------------
// C[m,h] = sum_i inter[m,i] * Wd[e,h,i]; out[token[m],h] += w[m]*C[m,h]
// Tile 256 x 256, same phase-split pipeline.
__global__ __launch_bounds__(512, 2) void moe_down(
    const unsigned short* __restrict__ inter,
    const unsigned short* __restrict__ Wd,
    float* __restrict__ out,
    const int* __restrict__ work_e, const int* __restrict__ work_r,
    const int* __restrict__ ntiles,
    const int* __restrict__ row_token, const float* __restrict__ row_weight) {
  const int tile = blockIdx.x;
  if (tile >= *ntiles) return;
  const int e = work_e[tile];
  const int row0 = work_r[tile];
  const int col0 = blockIdx.y * 256;   // h dim

  __shared__ unsigned short As[3][256 * 32];
  __shared__ unsigned short Bs[3][256 * 32];
  __shared__ int tok_s[256];
  __shared__ float w_s[256];

  const int tid = threadIdx.x;
  if (tid < 256) {
    tok_s[tid] = row_token[row0 + tid];
    w_s[tid] = row_weight[row0 + tid];
  }
  __syncthreads();

  const int lane = tid & 63;
  const int wave = tid >> 6;
  const int wm = wave >> 2, wn = wave & 3;
  const int p_l = lane & 7;
  const int ub  = lane >> 3;
  const int q_l = p_l ^ ub;
  const int srow = (ub << 1) | (q_l >> 2);
  const int scol = (q_l & 3) << 3;
  const int fm = lane & 15, fq = lane >> 4;

  const size_t a_base = (size_t)row0 * ID;
  const size_t b_base = ((size_t)e * HD + col0) * ID;

  f32x4 zero = {0.f, 0.f, 0.f, 0.f};
  f32x4 acc[8][4];
#pragma unroll
  for (int mi = 0; mi < 8; ++mi)
#pragma unroll
    for (int ni = 0; ni < 4; ++ni) acc[mi][ni] = zero;

  auto stageA = [&](int k0, int b) {
#pragma unroll
    for (int j = 0; j < 2; ++j) {
      const int rb = j * 128 + wave * 16;
      gl_lds16(inter + a_base + (size_t)(rb + srow) * ID + k0 + scol, &As[b][rb * 32]);
    }
  };
  auto stageB = [&](int k0, int b) {
#pragma unroll
    for (int j = 0; j < 2; ++j) {
      const int rb = j * 128 + wave * 16;
      gl_lds16(Wd + b_base + (size_t)(rb + srow) * ID + k0 + scol, &Bs[b][rb * 32]);
    }
  };

  stageA(0, 0); stageB(0, 0);
  stageA(32, 1); stageB(32, 1);
  asm volatile("s_waitcnt vmcnt(4)" ::: "memory");
  __builtin_amdgcn_s_barrier();
  __builtin_amdgcn_sched_barrier(0);

  int bufc = 0, buf2 = 2, k2 = 64;
  bf16x8 b4[4];
#pragma unroll 1
  for (int t = 0; t < NKD; ++t) {
    // ---- phase 0 ----
    if (t + 2 < NKD) stageA(k2, buf2);
    {
      bf16x8 af[4];
#pragma unroll
      for (int i = 0; i < 4; ++i)
        b4[i] = *(const bf16x8*)&Bs[bufc][swz_off(wn * 64 + i * 16 + fm, fq)];
#pragma unroll
      for (int i = 0; i < 4; ++i)
        af[i] = *(const bf16x8*)&As[bufc][swz_off(wm * 128 + i * 16 + fm, fq)];
      __builtin_amdgcn_s_setprio(1);
#pragma unroll
      for (int mi = 0; mi < 4; ++mi)
#pragma unroll
        for (int ni = 0; ni < 4; ++ni)
          acc[mi][ni] = __builtin_amdgcn_mfma_f32_16x16x32_bf16(af[mi], b4[ni], acc[mi][ni], 0, 0, 0);
      __builtin_amdgcn_s_setprio(0);
    }
    __builtin_amdgcn_s_barrier();
    __builtin_amdgcn_sched_barrier(0);
    // ---- phase 1 ----
    if (t + 2 < NKD) stageB(k2, buf2);
    {
      bf16x8 af[4];
#pragma unroll
      for (int i = 0; i < 4; ++i)
        af[i] = *(const bf16x8*)&As[bufc][swz_off(wm * 128 + (4 + i) * 16 + fm, fq)];
      __builtin_amdgcn_s_setprio(1);
#pragma unroll
      for (int mi = 0; mi < 4; ++mi)
#pragma unroll
        for (int ni = 0; ni < 4; ++ni)
          acc[4 + mi][ni] = __builtin_amdgcn_mfma_f32_16x16x32_bf16(af[mi], b4[ni], acc[4 + mi][ni], 0, 0, 0);
      __builtin_amdgcn_s_setprio(0);
    }
    if (t < NKD - 1) {
      if (t + 2 < NKD) asm volatile("s_waitcnt vmcnt(4)" ::: "memory");
      else             asm volatile("s_waitcnt vmcnt(0)" ::: "memory");
      __builtin_amdgcn_s_barrier();
      __builtin_amdgcn_sched_barrier(0);
    }
    k2 += 32;
    bufc = (bufc == 2) ? 0 : bufc + 1;
    buf2 = (buf2 == 2) ? 0 : buf2 + 1;
  }

#pragma unroll
  for (int mi = 0; mi < 8; ++mi)
#pragma unroll
    for (int ni = 0; ni < 4; ++ni)
#pragma unroll
      for (int r = 0; r < 4; ++r) {
        int rl = wm * 128 + mi * 16 + fq * 4 + r;
        int tok = tok_s[rl];
        if (tok >= 0) {
          int col = col0 + wn * 64 + ni * 16 + fm;
          atomicAdd(&out[(size_t)tok * HD + col], w_s[rl] * acc[mi][ni][r]);
        }
      }
}

// ---------------- host ------------------------------------------------------
extern "C" void kernel_launch(void* const* d_in, const int* in_sizes, int n_in,
                              void* d_out, int out_size, void* d_ws, size_t ws_size,
                              hipStream_t stream) {
  const float* hidden = (const float*)d_in[0];
  const int* topk_idx = (const int*)d_in[1];
  const float* topk_w = (const float*)d_in[2];
  const float* gate_w = (const float*)d_in[3];
  const float* up_w = (const float*)d_in[4];
  const float* down_w = (const float*)d_in[5];
  float* out = (float*)d_out;

  char* ws = (char*)d_ws;
  size_t o_gate = 0;
  size_t o_up   = o_gate + EIH * 2;
  size_t o_down = o_up + EIH * 2;
  size_t o_xg   = o_down + EIH * 2;
  size_t o_int  = o_xg + (size_t)MAXR * HD * 2;
  size_t o_tok  = o_int + (size_t)MAXR * ID * 2;
  size_t o_wgt  = o_tok + (size_t)MAXR * 4;
  size_t o_slot = o_wgt + (size_t)MAXR * 4;
  size_t o_small = o_slot + (size_t)NA * 4;

  unsigned short* gate_bf = (unsigned short*)(ws + o_gate);
  unsigned short* up_bf   = (unsigned short*)(ws + o_up);
  unsigned short* down_bf = (unsigned short*)(ws + o_down);
  unsigned short* Xg      = (unsigned short*)(ws + o_xg);
  unsigned short* inter   = (unsigned short*)(ws + o_int);
  int* row_token = (int*)(ws + o_tok);
  float* row_weight = (float*)(ws + o_wgt);
  int* slot_of = (int*)(ws + o_slot);
  int* cnt    = (int*)(ws + o_small);
  int* cnt2   = cnt + 8;
  int* seg    = cnt + 16;
  int* ntiles = cnt + 24;
  int* work_e = cnt + 32;
  int* work_r = cnt + 32 + MAXT;

  hipMemsetAsync(out, 0, (size_t)T_TOK * HD * 4, stream);
  hipMemsetAsync(cnt, 0, (32 + 2 * MAXT) * 4, stream);
  hipMemsetAsync(row_token, 0xFF, (size_t)MAXR * 4, stream);

  moe_count<<<NA / 256, 256, 0, stream>>>(topk_idx, cnt);
  moe_scan<<<1, 64, 0, stream>>>(cnt, seg, work_e, work_r, ntiles);
  moe_fill<<<NA / 256, 256, 0, stream>>>(topk_idx, topk_w, seg, cnt2,
                                         row_token, row_weight, slot_of);

  // mega1: gather (8192 blocks) + cast gate/up (2048 blocks)
  mega_gather_castgu<<<NA + NCGU, 256, 0, stream>>>(hidden, slot_of, Xg,
                                                    gate_w, up_w, gate_bf, up_bf);

  // mega2: gate/up GEMM (440 blocks), down-cast backfills (512 blocks)
  moe_gateup<<<NGEMM_GU + NCASTD, 512, 0, stream>>>(
      Xg, gate_bf, up_bf, inter, work_e, work_r, ntiles, down_w, down_bf);

  dim3 gridB(NTILE_G, HD / 256);   // 40 x 8
  moe_down<<<gridB, 512, 0, stream>>>(inter, down_bf, out, work_e, work_r, ntiles,
                                      row_token, row_weight);
}

// Round 3
// 629.469 us; speedup vs baseline: 1.0360x; 1.0360x over previous
//
#include <hip/hip_runtime.h>
#include <cstdint>
#include <cstddef>

#define T_TOK 4096
#define HD 2048
#define ID 1408
#define NE 8
#define NA (T_TOK * 2)        // 8192 assignments (K=2)
#define MAXR 10240            // 8192 + 8*255 padding headroom, mult of 256
#define MAXT 40               // max 256-row tiles (<= 39 actually)
#define EIH ((size_t)NE * ID * HD)
#define N4 ((int)(EIH / 4))   // float4 count per weight tensor = 5,767,168
#define NCGU 2048             // cast blocks for gate+up (merged with gather)
#define NCASTD 256            // cast blocks for down (merged with gateup, 1024 thr)
#define NTILE_G (MAXR / 256)  // 40
#define NGEMM_GU (NTILE_G * (ID / 128))  // 440 (divisible by 8 -> bijective XCD swizzle)
#define NKGU (HD / 32)        // 64 K-tiles
#define NKD  (ID / 32)        // 44 K-tiles

typedef __bf16 bf16x8 __attribute__((ext_vector_type(8)));
typedef float f32x4 __attribute__((ext_vector_type(4)));

__device__ __forceinline__ unsigned short f2bf(float f) {
  union { float f; unsigned int u; } c; c.f = f;
  unsigned int u = c.u;
  u += 0x7fffu + ((u >> 16) & 1u);   // round-to-nearest-even
  return (unsigned short)(u >> 16);
}

__device__ __forceinline__ void gl_lds16(const unsigned short* g, unsigned short* l) {
  __builtin_amdgcn_global_load_lds(
      (const __attribute__((address_space(1))) unsigned int*)g,
      (__attribute__((address_space(3))) unsigned int*)l, 16, 0, 0);
}

// XOR-swizzled Nx32 bf16 tile (64B rows, swizzle at 128B/2-row units):
// logical (row R, 16B chunk fq) lives at physical chunk p = q ^ ((R>>1)&7),
// q = (R&1)*4 + fq. Measured conflict-free (SQ_LDS_BANK_CONFLICT = 0).
__device__ __forceinline__ int swz_off(int R, int fq) {
  int q = ((R & 1) << 2) | fq;
  int p = q ^ ((R >> 1) & 7);
  return (R >> 1) * 64 + p * 8;
}

// ---------------- routing ---------------------------------------------------
__global__ void moe_count(const int* __restrict__ idx, int* __restrict__ cnt) {
  int a = blockIdx.x * 256 + threadIdx.x;
  if (a < NA) atomicAdd(&cnt[idx[a]], 1);
}

__global__ void moe_scan(const int* __restrict__ cnt, int* __restrict__ seg,
                         int* __restrict__ work_e, int* __restrict__ work_r,
                         int* __restrict__ ntiles) {
  if (blockIdx.x == 0 && threadIdx.x == 0) {
    int off = 0, nt = 0;
    for (int e = 0; e < NE; ++e) {
      seg[e] = off;
      int c = cnt[e];
      int tiles = (c + 255) >> 8;          // pad each expert to 256-row tiles
      for (int tb = 0; tb < tiles; ++tb) {
        work_e[nt] = e;
        work_r[nt] = off + tb * 256;
        ++nt;
      }
      off += tiles << 8;
    }
    *ntiles = nt;
  }
}

__global__ void moe_fill(const int* __restrict__ idx, const float* __restrict__ wts,
                         const int* __restrict__ seg, int* __restrict__ cnt2,
                         int* __restrict__ row_token, float* __restrict__ row_weight,
                         int* __restrict__ slot_of) {
  int a = blockIdx.x * 256 + threadIdx.x;
  if (a < NA) {
    int e = idx[a];
    int pos = atomicAdd(&cnt2[e], 1);
    int slot = seg[e] + pos;
    row_token[slot] = a >> 1;       // token id (K=2)
    row_weight[slot] = wts[a];
    slot_of[a] = slot;
  }
}

// ---------------- mega1: gather routed rows  +  cast gate/up fp32->bf16 ----
__global__ void mega_gather_castgu(
    const float* __restrict__ hidden, const int* __restrict__ slot_of,
    unsigned short* __restrict__ Xg,
    const float* __restrict__ gate_w, const float* __restrict__ up_w,
    unsigned short* __restrict__ gate_bf, unsigned short* __restrict__ ub_out) {
  const int bx = blockIdx.x;
  if (bx < NA) {
    const int slot = slot_of[bx];
    const int t = bx >> 1;
    const float4* src = (const float4*)(hidden + (size_t)t * HD);
    ushort4* dst = (ushort4*)(Xg + (size_t)slot * HD);
#pragma unroll
    for (int j = 0; j < 2; ++j) {
      int i = threadIdx.x + j * 256;
      float4 v = src[i];
      ushort4 o;
      o.x = f2bf(v.x); o.y = f2bf(v.y); o.z = f2bf(v.z); o.w = f2bf(v.w);
      dst[i] = o;
    }
  } else {
    const int cb = bx - NA;
    const int total = 2 * N4;
    for (int i = cb * 256 + threadIdx.x; i < total; i += NCGU * 256) {
      const float* s; unsigned short* t; int j = i;
      if (j < N4) { s = gate_w; t = gate_bf; }
      else { s = up_w; t = ub_out; j -= N4; }
      f32x4 v = __builtin_nontemporal_load((const f32x4*)s + j);
      ushort4 o;
      o.x = f2bf(v[0]); o.y = f2bf(v[1]); o.z = f2bf(v[2]); o.w = f2bf(v[3]);
      ((ushort4*)t)[j] = o;
    }
  }
}

// ---------------- mega2: gate+up GEMM (SwiGLU epilogue) + cast down_w ------
// Tile: 256 rows x 128 I-cols of BOTH gate and up (BNeff=256). 1024 threads =
// 16 waves (4M x 4N): wave owns 64 rows x 32 cols of both (SwiGLU in-wave).
// BK=32, 3 LDS buffers, stage tile t+2, ONE barrier + vmcnt(2) per K-tile.
// 16 waves/CU (4/SIMD) is the latency-hiding lever this round.
__global__ __launch_bounds__(1024, 4) void moe_gateup(
    const unsigned short* __restrict__ Xg,
    const unsigned short* __restrict__ Wg,
    const unsigned short* __restrict__ Wu,
    unsigned short* __restrict__ inter,
    const int* __restrict__ work_e, const int* __restrict__ work_r,
    const int* __restrict__ ntiles,
    const float* __restrict__ down_w, unsigned short* __restrict__ down_bf) {
  const int bx = blockIdx.x;
  if (bx >= NGEMM_GU) {
    // down-cast backfills the GEMM tail rounds
    const int cb = bx - NGEMM_GU;
    for (int i = cb * 1024 + threadIdx.x; i < N4; i += NCASTD * 1024) {
      f32x4 v = __builtin_nontemporal_load((const f32x4*)down_w + i);
      ushort4 o;
      o.x = f2bf(v[0]); o.y = f2bf(v[1]); o.z = f2bf(v[2]); o.w = f2bf(v[3]);
      ((ushort4*)down_bf)[i] = o;
    }
    return;
  }
  // bijective XCD swizzle (440 % 8 == 0); consecutive g share the B panel
  const int g = (bx & 7) * (NGEMM_GU / 8) + (bx >> 3);
  const int tile = g % NTILE_G;
  if (tile >= *ntiles) return;
  const int e = work_e[tile];
  const int row0 = work_r[tile];
  const int col0 = (g / NTILE_G) * 128;

  __shared__ unsigned short As[3][256 * 32];   // 48 KB
  __shared__ unsigned short Bs[3][256 * 32];   // 48 KB (rows 0-127 gate, 128-255 up)

  const int tid = threadIdx.x;
  const int lane = tid & 63;
  const int wave = tid >> 6;          // 0..15
  const int wm = wave >> 2, wn = wave & 3;
  const int p_l = lane & 7;
  const int ub  = lane >> 3;
  const int q_l = p_l ^ ub;
  const int srow = (ub << 1) | (q_l >> 2);
  const int scol = (q_l & 3) << 3;
  const int fm = lane & 15, fq = lane >> 4;

  const size_t a_base = (size_t)row0 * HD;
  const size_t b_base = ((size_t)e * ID + col0) * HD;
  const int rb = wave << 4;           // staging row block, 16 rows/wave

  f32x4 zero = {0.f, 0.f, 0.f, 0.f};
  f32x4 accg[4][2], accu[4][2];
#pragma unroll
  for (int mi = 0; mi < 4; ++mi)
#pragma unroll
    for (int ni = 0; ni < 2; ++ni) { accg[mi][ni] = zero; accu[mi][ni] = zero; }

  // one gl_lds per wave per matrix per K-tile
  auto stageA = [&](int k0, int b) {
    gl_lds16(Xg + a_base + (size_t)(rb + srow) * HD + k0 + scol, &As[b][rb * 32]);
  };
  auto stageB = [&](int k0, int b) {
    const unsigned short* src = (wave < 8)
        ? (Wg + b_base + (size_t)(rb + srow) * HD + k0 + scol)
        : (Wu + b_base + (size_t)(rb - 128 + srow) * HD + k0 + scol);
    gl_lds16(src, &Bs[b][rb * 32]);
  };

  // prologue: tiles 0,1 (4 loads/wave); wait tile 0 landed (2 in flight)
  stageA(0, 0); stageB(0, 0);
  stageA(32, 1); stageB(32, 1);
  asm volatile("s_waitcnt vmcnt(2)" ::: "memory");
  __builtin_amdgcn_s_barrier();
  __builtin_amdgcn_sched_barrier(0);

  int bufc = 0, buf2 = 2, k2 = 64;
#pragma unroll 1
  for (int t = 0; t < NKGU; ++t) {
    if (t + 2 < NKGU) { stageA(k2, buf2); stageB(k2, buf2); }
    {
      bf16x8 af[4], bg[2], bu[2];
#pragma unroll
      for (int i = 0; i < 2; ++i) {
        bg[i] = *(const bf16x8*)&Bs[bufc][swz_off(wn * 32 + i * 16 + fm, fq)];
        bu[i] = *(const bf16x8*)&Bs[bufc][swz_off(128 + wn * 32 + i * 16 + fm, fq)];
      }
#pragma unroll
      for (int i = 0; i < 4; ++i)
        af[i] = *(const bf16x8*)&As[bufc][swz_off(wm * 64 + i * 16 + fm, fq)];
      __builtin_amdgcn_s_setprio(1);
#pragma unroll
      for (int mi = 0; mi < 4; ++mi)
#pragma unroll
        for (int ni = 0; ni < 2; ++ni) {
          accg[mi][ni] = __builtin_amdgcn_mfma_f32_16x16x32_bf16(af[mi], bg[ni], accg[mi][ni], 0, 0, 0);
          accu[mi][ni] = __builtin_amdgcn_mfma_f32_16x16x32_bf16(af[mi], bu[ni], accu[mi][ni], 0, 0, 0);
        }
      __builtin_amdgcn_s_setprio(0);
    }
    if (t < NKGU - 1) {
      if (t + 2 < NKGU) asm volatile("s_waitcnt vmcnt(2)" ::: "memory");
      else              asm volatile("s_waitcnt vmcnt(0)" ::: "memory");
      __builtin_amdgcn_s_barrier();
      __builtin_amdgcn_sched_barrier(0);
    }
    k2 += 32;
    bufc = (bufc == 2) ? 0 : bufc + 1;
    buf2 = (buf2 == 2) ? 0 : buf2 + 1;
  }

  // SwiGLU epilogue -> inter (bf16). Padded rows computed too (harmless).
#pragma unroll
  for (int mi = 0; mi < 4; ++mi)
#pragma unroll
    for (int ni = 0; ni < 2; ++ni)
#pragma unroll
      for (int r = 0; r < 4; ++r) {
        float gg = accg[mi][ni][r];
        float u = accu[mi][ni][r];
        float v = (gg / (1.0f + __expf(-gg))) * u;
        int row = row0 + wm * 64 + mi * 16 + fq * 4 + r;
        int col = col0 + wn * 32 + ni * 16 + fm;
        inter[(size_t)row * ID + col] = f2bf(v);
      }
}

// ---------------- phase B: down GEMM, weighted atomic scatter ---------------
// C[m,h] = sum_i inter[m,i] * Wd[e,h,i]; out[token[m],h] += w[m]*C[m,h]
// Tile 256 x 256, 1024 threads / 16 waves (4M x 4N), same pipeline.
__global__ __launch_bounds__(1024, 4) void moe_down(
    const unsigned short* __restrict__ inter,
    const unsigned short* __restrict__ Wd,
    float* __restrict__ out,
    const int* __restrict__ work_e, const int* __restrict__ work_r,
    const int* __restrict__ ntiles,
    const int* __restrict__ row_token, const float* __restrict__ row_weight) {
  const int tile = blockIdx.x;
  if (tile >= *ntiles) return;
  const int e = work_e[tile];
  const int row0 = work_r[tile];
  const int col0 = blockIdx.y * 256;   // h dim

  __shared__ unsigned short As[3][256 * 32];
  __shared__ unsigned short Bs[3][256 * 32];
  __shared__ int tok_s[256];
  __shared__ float w_s[256];

  const int tid = threadIdx.x;
  if (tid < 256) {
    tok_s[tid] = row_token[row0 + tid];
    w_s[tid] = row_weight[row0 + tid];
  }

  const int lane = tid & 63;
  const int wave = tid >> 6;          // 0..15
  const int wm = wave >> 2, wn = wave & 3;
  const int p_l = lane & 7;
  const int ub  = lane >> 3;
  const int q_l = p_l ^ ub;
  const int srow = (ub << 1) | (q_l >> 2);
  const int scol = (q_l & 3) << 3;
  const int fm = lane & 15, fq = lane >> 4;

  const size_t a_base = (size_t)row0 * ID;
  const size_t b_base = ((size_t)e * HD + col0) * ID;
  const int rb = wave << 4;

  f32x4 zero = {0.f, 0.f, 0.f, 0.f};
  f32x4 acc[4][4];
#pragma unroll
  for (int mi = 0; mi < 4; ++mi)
#pragma unroll
    for (int ni = 0; ni < 4; ++ni) acc[mi][ni] = zero;

  auto stageA = [&](int k0, int b) {
    gl_lds16(inter + a_base + (size_t)(rb + srow) * ID + k0 + scol, &As[b][rb * 32]);
  };
  auto stageB = [&](int k0, int b) {
    gl_lds16(Wd + b_base + (size_t)(rb + srow) * ID + k0 + scol, &Bs[b][rb * 32]);
  };

  stageA(0, 0); stageB(0, 0);
  stageA(32, 1); stageB(32, 1);
  asm volatile("s_waitcnt vmcnt(2)" ::: "memory");
  __builtin_amdgcn_s_barrier();
  __builtin_amdgcn_sched_barrier(0);

  int bufc = 0, buf2 = 2, k2 = 64;
#pragma unroll 1
  for (int t = 0; t < NKD; ++t) {
    if (t + 2 < NKD) { stageA(k2, buf2); stageB(k2, buf2); }
    {
      bf16x8 af[4], b4[4];
#pragma unroll
      for (int i = 0; i < 4; ++i)
        b4[i] = *(const bf16x8*)&Bs[bufc][swz_off(wn * 64 + i * 16 + fm, fq)];
#pragma unroll
      for (int i = 0; i < 4; ++i)
        af[i] = *(const bf16x8*)&As[bufc][swz_off(wm * 64 + i * 16 + fm, fq)];
      __builtin_amdgcn_s_setprio(1);
#pragma unroll
      for (int mi = 0; mi < 4; ++mi)
#pragma unroll
        for (int ni = 0; ni < 4; ++ni)
          acc[mi][ni] = __builtin_amdgcn_mfma_f32_16x16x32_bf16(af[mi], b4[ni], acc[mi][ni], 0, 0, 0);
      __builtin_amdgcn_s_setprio(0);
    }
    if (t < NKD - 1) {
      if (t + 2 < NKD) asm volatile("s_waitcnt vmcnt(2)" ::: "memory");
      else             asm volatile("s_waitcnt vmcnt(0)" ::: "memory");
      __builtin_amdgcn_s_barrier();
      __builtin_amdgcn_sched_barrier(0);
    }
    k2 += 32;
    bufc = (bufc == 2) ? 0 : bufc + 1;
    buf2 = (buf2 == 2) ? 0 : buf2 + 1;
  }

#pragma unroll
  for (int mi = 0; mi < 4; ++mi)
#pragma unroll
    for (int ni = 0; ni < 4; ++ni)
#pragma unroll
      for (int r = 0; r < 4; ++r) {
        int rl = wm * 64 + mi * 16 + fq * 4 + r;
        int tok = tok_s[rl];
        if (tok >= 0) {
          int col = col0 + wn * 64 + ni * 16 + fm;
          atomicAdd(&out[(size_t)tok * HD + col], w_s[rl] * acc[mi][ni][r]);
        }
      }
}

// ---------------- host ------------------------------------------------------
extern "C" void kernel_launch(void* const* d_in, const int* in_sizes, int n_in,
                              void* d_out, int out_size, void* d_ws, size_t ws_size,
                              hipStream_t stream) {
  const float* hidden = (const float*)d_in[0];
  const int* topk_idx = (const int*)d_in[1];
  const float* topk_w = (const float*)d_in[2];
  const float* gate_w = (const float*)d_in[3];
  const float* up_w = (const float*)d_in[4];
  const float* down_w = (const float*)d_in[5];
  float* out = (float*)d_out;

  char* ws = (char*)d_ws;
  size_t o_gate = 0;
  size_t o_up   = o_gate + EIH * 2;
  size_t o_down = o_up + EIH * 2;
  size_t o_xg   = o_down + EIH * 2;
  size_t o_int  = o_xg + (size_t)MAXR * HD * 2;
  size_t o_tok  = o_int + (size_t)MAXR * ID * 2;
  size_t o_wgt  = o_tok + (size_t)MAXR * 4;
  size_t o_slot = o_wgt + (size_t)MAXR * 4;
  size_t o_small = o_slot + (size_t)NA * 4;

  unsigned short* gate_bf = (unsigned short*)(ws + o_gate);
  unsigned short* up_bf   = (unsigned short*)(ws + o_up);
  unsigned short* down_bf = (unsigned short*)(ws + o_down);
  unsigned short* Xg      = (unsigned short*)(ws + o_xg);
  unsigned short* inter   = (unsigned short*)(ws + o_int);
  int* row_token = (int*)(ws + o_tok);
  float* row_weight = (float*)(ws + o_wgt);
  int* slot_of = (int*)(ws + o_slot);
  int* cnt    = (int*)(ws + o_small);
  int* cnt2   = cnt + 8;
  int* seg    = cnt + 16;
  int* ntiles = cnt + 24;
  int* work_e = cnt + 32;
  int* work_r = cnt + 32 + MAXT;

  hipMemsetAsync(out, 0, (size_t)T_TOK * HD * 4, stream);
  hipMemsetAsync(cnt, 0, (32 + 2 * MAXT) * 4, stream);
  hipMemsetAsync(row_token, 0xFF, (size_t)MAXR * 4, stream);

  moe_count<<<NA / 256, 256, 0, stream>>>(topk_idx, cnt);
  moe_scan<<<1, 64, 0, stream>>>(cnt, seg, work_e, work_r, ntiles);
  moe_fill<<<NA / 256, 256, 0, stream>>>(topk_idx, topk_w, seg, cnt2,
                                         row_token, row_weight, slot_of);

  // mega1: gather (8192 blocks) + cast gate/up (2048 blocks)
  mega_gather_castgu<<<NA + NCGU, 256, 0, stream>>>(hidden, slot_of, Xg,
                                                    gate_w, up_w, gate_bf, up_bf);

  // mega2: gate/up GEMM (440 blocks, 1024 thr), down-cast backfills (256 blocks)
  moe_gateup<<<NGEMM_GU + NCASTD, 1024, 0, stream>>>(
      Xg, gate_bf, up_bf, inter, work_e, work_r, ntiles, down_w, down_bf);

  dim3 gridB(NTILE_G, HD / 256);   // 40 x 8
  moe_down<<<gridB, 1024, 0, stream>>>(inter, down_bf, out, work_e, work_r, ntiles,
                                       row_token, row_weight);
}

// Round 4
// 620.583 us; speedup vs baseline: 1.0508x; 1.0143x over previous
//
#include <hip/hip_runtime.h>
#include <cstdint>
#include <cstddef>

#define T_TOK 4096
#define HD 2048
#define ID 1408
#define NE 8
#define NA (T_TOK * 2)        // 8192 assignments (K=2)
#define MAXR 10240            // 8192 + 8*255 padding headroom, mult of 256
#define MAXT 40               // max 256-row tiles (<= 39 actually)
#define EIH ((size_t)NE * ID * HD)
#define N4 ((int)(EIH / 4))   // float4 count per weight tensor = 5,767,168
#define NCGU 2048             // cast blocks for gate+up (merged with gather)
#define NCASTD 512            // cast blocks for down (merged with gateup, 512 thr)
#define NTILE_G (MAXR / 256)  // 40
#define NGEMM_GU (NTILE_G * (ID / 128))  // 440 (divisible by 8 -> bijective XCD swizzle)
#define NKGU (HD / 64)        // 32 K-tiles (BK=64)
#define NKD  (ID / 64)        // 22 K-tiles

typedef __bf16 bf16x8 __attribute__((ext_vector_type(8)));
typedef float f32x4 __attribute__((ext_vector_type(4)));

#define MFMA16 __builtin_amdgcn_mfma_f32_16x16x32_bf16
#define LD8(base, off) (*(const bf16x8*)&(base)[(off)])

__device__ __forceinline__ unsigned short f2bf(float f) {
  union { float f; unsigned int u; } c; c.f = f;
  unsigned int u = c.u;
  u += 0x7fffu + ((u >> 16) & 1u);   // round-to-nearest-even
  return (unsigned short)(u >> 16);
}

__device__ __forceinline__ void gl_lds16(const unsigned short* g, unsigned short* l) {
  __builtin_amdgcn_global_load_lds(
      (const __attribute__((address_space(1))) unsigned int*)g,
      (__attribute__((address_space(3))) unsigned int*)l, 16, 0, 0);
}

// XOR-swizzled [256]x[32] bf16 slab (64B rows, swizzle at 128B/2-row units):
// logical (row R, 16B chunk fq) lives at physical chunk p = q ^ ((R>>1)&7),
// q = (R&1)*4 + fq. Measured conflict-free (SQ_LDS_BANK_CONFLICT = 0).
__device__ __forceinline__ int swz_off(int R, int fq) {
  int q = ((R & 1) << 2) | fq;
  int p = q ^ ((R >> 1) & 7);
  return (R >> 1) * 64 + p * 8;
}
// buf layout: 2 K-slabs of [256 phys rows][32 elems]; ks selects slab.
__device__ __forceinline__ int lds_off(int ks, int P, int fq) {
  return ks * 8192 + swz_off(P, fq);
}

// ---------------- routing ---------------------------------------------------
__global__ void moe_count(const int* __restrict__ idx, int* __restrict__ cnt) {
  int a = blockIdx.x * 256 + threadIdx.x;
  if (a < NA) atomicAdd(&cnt[idx[a]], 1);
}

__global__ void moe_scan(const int* __restrict__ cnt, int* __restrict__ seg,
                         int* __restrict__ work_e, int* __restrict__ work_r,
                         int* __restrict__ ntiles) {
  if (blockIdx.x == 0 && threadIdx.x == 0) {
    int off = 0, nt = 0;
    for (int e = 0; e < NE; ++e) {
      seg[e] = off;
      int c = cnt[e];
      int tiles = (c + 255) >> 8;          // pad each expert to 256-row tiles
      for (int tb = 0; tb < tiles; ++tb) {
        work_e[nt] = e;
        work_r[nt] = off + tb * 256;
        ++nt;
      }
      off += tiles << 8;
    }
    *ntiles = nt;
  }
}

__global__ void moe_fill(const int* __restrict__ idx, const float* __restrict__ wts,
                         const int* __restrict__ seg, int* __restrict__ cnt2,
                         int* __restrict__ row_token, float* __restrict__ row_weight,
                         int* __restrict__ slot_of) {
  int a = blockIdx.x * 256 + threadIdx.x;
  if (a < NA) {
    int e = idx[a];
    int pos = atomicAdd(&cnt2[e], 1);
    int slot = seg[e] + pos;
    row_token[slot] = a >> 1;       // token id (K=2)
    row_weight[slot] = wts[a];
    slot_of[a] = slot;
  }
}

// ---------------- mega1: gather routed rows  +  cast gate/up fp32->bf16 ----
__global__ void mega_gather_castgu(
    const float* __restrict__ hidden, const int* __restrict__ slot_of,
    unsigned short* __restrict__ Xg,
    const float* __restrict__ gate_w, const float* __restrict__ up_w,
    unsigned short* __restrict__ gate_bf, unsigned short* __restrict__ ub_out) {
  const int bx = blockIdx.x;
  if (bx < NA) {
    const int slot = slot_of[bx];
    const int t = bx >> 1;
    const float4* src = (const float4*)(hidden + (size_t)t * HD);
    ushort4* dst = (ushort4*)(Xg + (size_t)slot * HD);
#pragma unroll
    for (int j = 0; j < 2; ++j) {
      int i = threadIdx.x + j * 256;
      float4 v = src[i];
      ushort4 o;
      o.x = f2bf(v.x); o.y = f2bf(v.y); o.z = f2bf(v.z); o.w = f2bf(v.w);
      dst[i] = o;
    }
  } else {
    const int cb = bx - NA;
    const int total = 2 * N4;
    for (int i = cb * 256 + threadIdx.x; i < total; i += NCGU * 256) {
      const float* s; unsigned short* t; int j = i;
      if (j < N4) { s = gate_w; t = gate_bf; }
      else { s = up_w; t = ub_out; j -= N4; }
      f32x4 v = __builtin_nontemporal_load((const f32x4*)s + j);
      ushort4 o;
      o.x = f2bf(v[0]); o.y = f2bf(v[1]); o.z = f2bf(v[2]); o.w = f2bf(v[3]);
      ((ushort4*)t)[j] = o;
    }
  }
}

// ---------------- mega2: gate+up GEMM (8-phase template) + cast down_w ------
// Tile 256 rows x 128 I-cols of BOTH gate and up. 512 thr / 8 waves (2M x 4N);
// wave owns 128 rows x (32 gate + 32 up). BK=64 (2 swizzled 32-slabs).
// 2 LDS dbufs; 4 phases per K-tile; one half-tile staged per phase into buf^1
// (stage order A0,Bg,Bu,A1 = need order); counted vmcnt(4); setprio on MFMA.
// A halves quadrant-interleaved: phys = h*128 + wm*64 + r6 for logical
// row wm*128 + h*64 + r6 (h = m-quadrant). B halves: gate rows 0-127 phys,
// up rows 128-255 phys (identity within panel).
__global__ __launch_bounds__(512, 2) void moe_gateup(
    const unsigned short* __restrict__ Xg,
    const unsigned short* __restrict__ Wg,
    const unsigned short* __restrict__ Wu,
    unsigned short* __restrict__ inter,
    const int* __restrict__ work_e, const int* __restrict__ work_r,
    const int* __restrict__ ntiles,
    const float* __restrict__ down_w, unsigned short* __restrict__ down_bf) {
  const int bx = blockIdx.x;
  if (bx >= NGEMM_GU) {
    const int cb = bx - NGEMM_GU;
    for (int i = cb * 512 + threadIdx.x; i < N4; i += NCASTD * 512) {
      f32x4 v = __builtin_nontemporal_load((const f32x4*)down_w + i);
      ushort4 o;
      o.x = f2bf(v[0]); o.y = f2bf(v[1]); o.z = f2bf(v[2]); o.w = f2bf(v[3]);
      ((ushort4*)down_bf)[i] = o;
    }
    return;
  }
  // bijective XCD swizzle (440 % 8 == 0)
  const int g = (bx & 7) * (NGEMM_GU / 8) + (bx >> 3);
  const int tile = g % NTILE_G;
  if (tile >= *ntiles) return;
  const int e = work_e[tile];
  const int row0 = work_r[tile];
  const int col0 = (g / NTILE_G) * 128;

  __shared__ unsigned short As[2][16384];   // 2 bufs x (2 slabs x 256 x 32) = 64 KB
  __shared__ unsigned short Bs[2][16384];   // 64 KB

  const int tid = threadIdx.x;
  const int lane = tid & 63;
  const int wave = tid >> 6;          // 0..7
  const int wm = wave >> 2, wn = wave & 3;
  const int p_l = lane & 7;
  const int ub  = lane >> 3;
  const int q_l = p_l ^ ub;
  const int srow = (ub << 1) | (q_l >> 2);
  const int scol = (q_l & 3) << 3;
  const int fm = lane & 15, fq = lane >> 4;

  const size_t a_base = (size_t)row0 * HD;
  const size_t b_base = ((size_t)e * ID + col0) * HD;

  f32x4 zero = {0.f, 0.f, 0.f, 0.f};
  f32x4 accg[8][2], accu[8][2];
#pragma unroll
  for (int mi = 0; mi < 8; ++mi)
#pragma unroll
    for (int j = 0; j < 2; ++j) { accg[mi][j] = zero; accu[mi][j] = zero; }

  auto stA = [&](int k0, int b, int h) {   // A half h -> 128 phys rows h*128..
    const int abase = ((wave >> 2) << 7) + (h << 6) + ((wave & 3) << 4);
    const int pp = (h << 7) + (wave << 4);
#pragma unroll
    for (int s = 0; s < 2; ++s)
      gl_lds16(Xg + a_base + (size_t)(abase + srow) * HD + k0 + s * 32 + scol,
               &As[b][s * 8192 + pp * 32]);
  };
  auto stB = [&](int k0, int b, int h) {   // h=0 gate, h=1 up
    const unsigned short* W = h ? Wu : Wg;
    const int pp = (h << 7) + (wave << 4);
#pragma unroll
    for (int s = 0; s < 2; ++s)
      gl_lds16(W + b_base + (size_t)((wave << 4) + srow) * HD + k0 + s * 32 + scol,
               &Bs[b][s * 8192 + pp * 32]);
  };

  // prologue: tile 0 halves in need-order; vmcnt(4) -> A0,Bg landed
  stA(0, 0, 0); stB(0, 0, 0); stB(0, 0, 1); stA(0, 0, 1);
  asm volatile("s_waitcnt vmcnt(4)" ::: "memory");
  __builtin_amdgcn_s_barrier();

  bf16x8 a[4][2], bg[2][2], bu[2][2];
#pragma unroll 1
  for (int t = 0; t < NKGU; ++t) {
    const int k1 = (t + 1) << 6;
    const bool pf = (t + 1 < NKGU);
    const unsigned short* Ab = As[t & 1];
    const unsigned short* Bb = Bs[t & 1];
    const int bn = (t & 1) ^ 1;

    // ---- P1: read A-m0 + bg | stage A0(t+1) | MFMA m0 x gate ----
#pragma unroll
    for (int i = 0; i < 4; ++i)
#pragma unroll
      for (int ks = 0; ks < 2; ++ks)
        a[i][ks] = LD8(Ab, lds_off(ks, wm * 64 + i * 16 + fm, fq));
#pragma unroll
    for (int j = 0; j < 2; ++j)
#pragma unroll
      for (int ks = 0; ks < 2; ++ks)
        bg[j][ks] = LD8(Bb, lds_off(ks, wn * 32 + j * 16 + fm, fq));
    if (pf) stA(k1, bn, 0);
    __builtin_amdgcn_s_barrier();
    asm volatile("s_waitcnt lgkmcnt(0)" ::: "memory");
    __builtin_amdgcn_sched_barrier(0);
    __builtin_amdgcn_s_setprio(1);
#pragma unroll
    for (int mi = 0; mi < 4; ++mi)
#pragma unroll
      for (int j = 0; j < 2; ++j)
#pragma unroll
        for (int ks = 0; ks < 2; ++ks)
          accg[mi][j] = MFMA16(a[mi][ks], bg[j][ks], accg[mi][j], 0, 0, 0);
    __builtin_amdgcn_s_setprio(0);
    if (pf) asm volatile("s_waitcnt vmcnt(4)" ::: "memory");
    else    asm volatile("s_waitcnt vmcnt(2)" ::: "memory");
    __builtin_amdgcn_s_barrier();

    // ---- P2: read bu | stage Bg(t+1) | MFMA m0 x up ----
#pragma unroll
    for (int j = 0; j < 2; ++j)
#pragma unroll
      for (int ks = 0; ks < 2; ++ks)
        bu[j][ks] = LD8(Bb, lds_off(ks, 128 + wn * 32 + j * 16 + fm, fq));
    if (pf) stB(k1, bn, 0);
    __builtin_amdgcn_s_barrier();
    asm volatile("s_waitcnt lgkmcnt(0)" ::: "memory");
    __builtin_amdgcn_sched_barrier(0);
    __builtin_amdgcn_s_setprio(1);
#pragma unroll
    for (int mi = 0; mi < 4; ++mi)
#pragma unroll
      for (int j = 0; j < 2; ++j)
#pragma unroll
        for (int ks = 0; ks < 2; ++ks)
          accu[mi][j] = MFMA16(a[mi][ks], bu[j][ks], accu[mi][j], 0, 0, 0);
    __builtin_amdgcn_s_setprio(0);
    if (pf) asm volatile("s_waitcnt vmcnt(4)" ::: "memory");
    else    asm volatile("s_waitcnt vmcnt(0)" ::: "memory");
    __builtin_amdgcn_s_barrier();

    // ---- P3: read A-m1 | stage Bu(t+1) | MFMA m1 x up ----
#pragma unroll
    for (int i = 0; i < 4; ++i)
#pragma unroll
      for (int ks = 0; ks < 2; ++ks)
        a[i][ks] = LD8(Ab, lds_off(ks, 128 + wm * 64 + i * 16 + fm, fq));
    if (pf) stB(k1, bn, 1);
    __builtin_amdgcn_s_barrier();
    asm volatile("s_waitcnt lgkmcnt(0)" ::: "memory");
    __builtin_amdgcn_sched_barrier(0);
    __builtin_amdgcn_s_setprio(1);
#pragma unroll
    for (int mi = 0; mi < 4; ++mi)
#pragma unroll
      for (int j = 0; j < 2; ++j)
#pragma unroll
        for (int ks = 0; ks < 2; ++ks)
          accu[4 + mi][j] = MFMA16(a[mi][ks], bu[j][ks], accu[4 + mi][j], 0, 0, 0);
    __builtin_amdgcn_s_setprio(0);
    __builtin_amdgcn_s_barrier();

    // ---- P4: stage A1(t+1) | MFMA m1 x gate (bg regs still live) ----
    if (pf) stA(k1, bn, 1);
    __builtin_amdgcn_s_barrier();
    __builtin_amdgcn_s_setprio(1);
#pragma unroll
    for (int mi = 0; mi < 4; ++mi)
#pragma unroll
      for (int j = 0; j < 2; ++j)
#pragma unroll
        for (int ks = 0; ks < 2; ++ks)
          accg[4 + mi][j] = MFMA16(a[mi][ks], bg[j][ks], accg[4 + mi][j], 0, 0, 0);
    __builtin_amdgcn_s_setprio(0);
    if (pf) asm volatile("s_waitcnt vmcnt(4)" ::: "memory");
    __builtin_amdgcn_s_barrier();
  }

  // SwiGLU epilogue -> inter (bf16). Padded rows computed too (harmless).
#pragma unroll
  for (int mi = 0; mi < 8; ++mi)
#pragma unroll
    for (int j = 0; j < 2; ++j)
#pragma unroll
      for (int r = 0; r < 4; ++r) {
        float gg = accg[mi][j][r];
        float u = accu[mi][j][r];
        float v = (gg / (1.0f + __expf(-gg))) * u;
        int row = row0 + wm * 128 + mi * 16 + fq * 4 + r;
        int col = col0 + wn * 32 + j * 16 + fm;
        inter[(size_t)row * ID + col] = f2bf(v);
      }
}

// ---------------- phase B: down GEMM (8-phase template), atomic scatter -----
// C[m,h] = sum_i inter[m,i] * Wd[e,h,i]; out[token[m],h] += w[m]*C[m,h]
// Tile 256 x 256; wave owns 128 x 64. B n-quadrants interleaved:
// phys = nq*128 + wn*32 + r5 for logical row wn*64 + nq*32 + r5.
__global__ __launch_bounds__(512, 2) void moe_down(
    const unsigned short* __restrict__ inter,
    const unsigned short* __restrict__ Wd,
    float* __restrict__ out,
    const int* __restrict__ work_e, const int* __restrict__ work_r,
    const int* __restrict__ ntiles,
    const int* __restrict__ row_token, const float* __restrict__ row_weight) {
  const int tile = blockIdx.x;
  if (tile >= *ntiles) return;
  const int e = work_e[tile];
  const int row0 = work_r[tile];
  const int col0 = blockIdx.y * 256;   // h dim

  __shared__ unsigned short As[2][16384];
  __shared__ unsigned short Bs[2][16384];
  __shared__ int tok_s[256];
  __shared__ float w_s[256];

  const int tid = threadIdx.x;
  if (tid < 256) {
    tok_s[tid] = row_token[row0 + tid];
    w_s[tid] = row_weight[row0 + tid];
  }

  const int lane = tid & 63;
  const int wave = tid >> 6;
  const int wm = wave >> 2, wn = wave & 3;
  const int p_l = lane & 7;
  const int ub  = lane >> 3;
  const int q_l = p_l ^ ub;
  const int srow = (ub << 1) | (q_l >> 2);
  const int scol = (q_l & 3) << 3;
  const int fm = lane & 15, fq = lane >> 4;

  const size_t a_base = (size_t)row0 * ID;
  const size_t b_base = ((size_t)e * HD + col0) * ID;

  f32x4 zero = {0.f, 0.f, 0.f, 0.f};
  f32x4 acc[8][4];
#pragma unroll
  for (int mi = 0; mi < 8; ++mi)
#pragma unroll
    for (int j = 0; j < 4; ++j) acc[mi][j] = zero;

  auto stA = [&](int k0, int b, int h) {
    const int abase = ((wave >> 2) << 7) + (h << 6) + ((wave & 3) << 4);
    const int pp = (h << 7) + (wave << 4);
#pragma unroll
    for (int s = 0; s < 2; ++s)
      gl_lds16(inter + a_base + (size_t)(abase + srow) * ID + k0 + s * 32 + scol,
               &As[b][s * 8192 + pp * 32]);
  };
  auto stB = [&](int k0, int b, int h) {   // h = n-quadrant
    const int bbase = ((wave >> 1) << 6) + (h << 5) + ((wave & 1) << 4);
    const int pp = (h << 7) + (wave << 4);
#pragma unroll
    for (int s = 0; s < 2; ++s)
      gl_lds16(Wd + b_base + (size_t)(bbase + srow) * ID + k0 + s * 32 + scol,
               &Bs[b][s * 8192 + pp * 32]);
  };

  stA(0, 0, 0); stB(0, 0, 0); stB(0, 0, 1); stA(0, 0, 1);
  asm volatile("s_waitcnt vmcnt(4)" ::: "memory");
  __builtin_amdgcn_s_barrier();

  bf16x8 a[4][2], b0[2][2], b1[2][2];
#pragma unroll 1
  for (int t = 0; t < NKD; ++t) {
    const int k1 = (t + 1) << 6;
    const bool pf = (t + 1 < NKD);
    const unsigned short* Ab = As[t & 1];
    const unsigned short* Bb = Bs[t & 1];
    const int bn = (t & 1) ^ 1;

    // ---- P1: read A-m0 + b-n0 | stage A0(t+1) | MFMA m0n0 ----
#pragma unroll
    for (int i = 0; i < 4; ++i)
#pragma unroll
      for (int ks = 0; ks < 2; ++ks)
        a[i][ks] = LD8(Ab, lds_off(ks, wm * 64 + i * 16 + fm, fq));
#pragma unroll
    for (int j = 0; j < 2; ++j)
#pragma unroll
      for (int ks = 0; ks < 2; ++ks)
        b0[j][ks] = LD8(Bb, lds_off(ks, wn * 32 + j * 16 + fm, fq));
    if (pf) stA(k1, bn, 0);
    __builtin_amdgcn_s_barrier();
    asm volatile("s_waitcnt lgkmcnt(0)" ::: "memory");
    __builtin_amdgcn_sched_barrier(0);
    __builtin_amdgcn_s_setprio(1);
#pragma unroll
    for (int mi = 0; mi < 4; ++mi)
#pragma unroll
      for (int j = 0; j < 2; ++j)
#pragma unroll
        for (int ks = 0; ks < 2; ++ks)
          acc[mi][j] = MFMA16(a[mi][ks], b0[j][ks], acc[mi][j], 0, 0, 0);
    __builtin_amdgcn_s_setprio(0);
    if (pf) asm volatile("s_waitcnt vmcnt(4)" ::: "memory");
    else    asm volatile("s_waitcnt vmcnt(2)" ::: "memory");
    __builtin_amdgcn_s_barrier();

    // ---- P2: read b-n1 | stage B0(t+1) | MFMA m0n1 ----
#pragma unroll
    for (int j = 0; j < 2; ++j)
#pragma unroll
      for (int ks = 0; ks < 2; ++ks)
        b1[j][ks] = LD8(Bb, lds_off(ks, 128 + wn * 32 + j * 16 + fm, fq));
    if (pf) stB(k1, bn, 0);
    __builtin_amdgcn_s_barrier();
    asm volatile("s_waitcnt lgkmcnt(0)" ::: "memory");
    __builtin_amdgcn_sched_barrier(0);
    __builtin_amdgcn_s_setprio(1);
#pragma unroll
    for (int mi = 0; mi < 4; ++mi)
#pragma unroll
      for (int j = 0; j < 2; ++j)
#pragma unroll
        for (int ks = 0; ks < 2; ++ks)
          acc[mi][2 + j] = MFMA16(a[mi][ks], b1[j][ks], acc[mi][2 + j], 0, 0, 0);
    __builtin_amdgcn_s_setprio(0);
    if (pf) asm volatile("s_waitcnt vmcnt(4)" ::: "memory");
    else    asm volatile("s_waitcnt vmcnt(0)" ::: "memory");
    __builtin_amdgcn_s_barrier();

    // ---- P3: read A-m1 | stage B1(t+1) | MFMA m1n1 ----
#pragma unroll
    for (int i = 0; i < 4; ++i)
#pragma unroll
      for (int ks = 0; ks < 2; ++ks)
        a[i][ks] = LD8(Ab, lds_off(ks, 128 + wm * 64 + i * 16 + fm, fq));
    if (pf) stB(k1, bn, 1);
    __builtin_amdgcn_s_barrier();
    asm volatile("s_waitcnt lgkmcnt(0)" ::: "memory");
    __builtin_amdgcn_sched_barrier(0);
    __builtin_amdgcn_s_setprio(1);
#pragma unroll
    for (int mi = 0; mi < 4; ++mi)
#pragma unroll
      for (int j = 0; j < 2; ++j)
#pragma unroll
        for (int ks = 0; ks < 2; ++ks)
          acc[4 + mi][2 + j] = MFMA16(a[mi][ks], b1[j][ks], acc[4 + mi][2 + j], 0, 0, 0);
    __builtin_amdgcn_s_setprio(0);
    __builtin_amdgcn_s_barrier();

    // ---- P4: stage A1(t+1) | MFMA m1n0 (b0 regs still live) ----
    if (pf) stA(k1, bn, 1);
    __builtin_amdgcn_s_barrier();
    __builtin_amdgcn_s_setprio(1);
#pragma unroll
    for (int mi = 0; mi < 4; ++mi)
#pragma unroll
      for (int j = 0; j < 2; ++j)
#pragma unroll
        for (int ks = 0; ks < 2; ++ks)
          acc[4 + mi][j] = MFMA16(a[mi][ks], b0[j][ks], acc[4 + mi][j], 0, 0, 0);
    __builtin_amdgcn_s_setprio(0);
    if (pf) asm volatile("s_waitcnt vmcnt(4)" ::: "memory");
    __builtin_amdgcn_s_barrier();
  }

#pragma unroll
  for (int mi = 0; mi < 8; ++mi)
#pragma unroll
    for (int j = 0; j < 4; ++j)
#pragma unroll
      for (int r = 0; r < 4; ++r) {
        int rl = wm * 128 + mi * 16 + fq * 4 + r;
        int tok = tok_s[rl];
        if (tok >= 0) {
          int col = col0 + wn * 64 + (j >> 1) * 32 + (j & 1) * 16 + fm;
          atomicAdd(&out[(size_t)tok * HD + col], w_s[rl] * acc[mi][j][r]);
        }
      }
}

// ---------------- host ------------------------------------------------------
extern "C" void kernel_launch(void* const* d_in, const int* in_sizes, int n_in,
                              void* d_out, int out_size, void* d_ws, size_t ws_size,
                              hipStream_t stream) {
  const float* hidden = (const float*)d_in[0];
  const int* topk_idx = (const int*)d_in[1];
  const float* topk_w = (const float*)d_in[2];
  const float* gate_w = (const float*)d_in[3];
  const float* up_w = (const float*)d_in[4];
  const float* down_w = (const float*)d_in[5];
  float* out = (float*)d_out;

  char* ws = (char*)d_ws;
  size_t o_gate = 0;
  size_t o_up   = o_gate + EIH * 2;
  size_t o_down = o_up + EIH * 2;
  size_t o_xg   = o_down + EIH * 2;
  size_t o_int  = o_xg + (size_t)MAXR * HD * 2;
  size_t o_tok  = o_int + (size_t)MAXR * ID * 2;
  size_t o_wgt  = o_tok + (size_t)MAXR * 4;
  size_t o_slot = o_wgt + (size_t)MAXR * 4;
  size_t o_small = o_slot + (size_t)NA * 4;

  unsigned short* gate_bf = (unsigned short*)(ws + o_gate);
  unsigned short* up_bf   = (unsigned short*)(ws + o_up);
  unsigned short* down_bf = (unsigned short*)(ws + o_down);
  unsigned short* Xg      = (unsigned short*)(ws + o_xg);
  unsigned short* inter   = (unsigned short*)(ws + o_int);
  int* row_token = (int*)(ws + o_tok);
  float* row_weight = (float*)(ws + o_wgt);
  int* slot_of = (int*)(ws + o_slot);
  int* cnt    = (int*)(ws + o_small);
  int* cnt2   = cnt + 8;
  int* seg    = cnt + 16;
  int* ntiles = cnt + 24;
  int* work_e = cnt + 32;
  int* work_r = cnt + 32 + MAXT;

  hipMemsetAsync(out, 0, (size_t)T_TOK * HD * 4, stream);
  hipMemsetAsync(cnt, 0, (32 + 2 * MAXT) * 4, stream);
  hipMemsetAsync(row_token, 0xFF, (size_t)MAXR * 4, stream);

  moe_count<<<NA / 256, 256, 0, stream>>>(topk_idx, cnt);
  moe_scan<<<1, 64, 0, stream>>>(cnt, seg, work_e, work_r, ntiles);
  moe_fill<<<NA / 256, 256, 0, stream>>>(topk_idx, topk_w, seg, cnt2,
                                         row_token, row_weight, slot_of);

  // mega1: gather (8192 blocks) + cast gate/up (2048 blocks)
  mega_gather_castgu<<<NA + NCGU, 256, 0, stream>>>(hidden, slot_of, Xg,
                                                    gate_w, up_w, gate_bf, up_bf);

  // mega2: gate/up GEMM (440 blocks), down-cast backfills (512 blocks)
  moe_gateup<<<NGEMM_GU + NCASTD, 512, 0, stream>>>(
      Xg, gate_bf, up_bf, inter, work_e, work_r, ntiles, down_w, down_bf);

  dim3 gridB(NTILE_G, HD / 256);   // 40 x 8
  moe_down<<<gridB, 512, 0, stream>>>(inter, down_bf, out, work_e, work_r, ntiles,
                                      row_token, row_weight);
}